// Round 8
// baseline (95.994 us; speedup 1.0000x reference)
//
#include <hip/hip_runtime.h>
#include <hip/hip_bf16.h>

#define B_ 64
#define T_ 4096
#define DQ_ 512
#define DF_ 256
#define H_ 8
#define D_ 64
#define EPS_ 1e-7f
#define NBLK 512        /* (b, qq): 8 blocks per batch, 512 rows each */
#define CHUNK 32        /* rows per staged chunk */
#define NCH 16          /* chunks per block */
#define PS_STRIDE 2304  /* per-block partial: 9 rows x 256 */
#define ROWB 1040       /* padded LDS row bytes (65 16B slots) */
#define SLOTS 2080      /* 32 rows x 65 slots (slot 64 = pad) */
#define BUFB (SLOTS * 16)

typedef __attribute__((ext_vector_type(8))) short short8;
typedef __attribute__((ext_vector_type(4))) float f32x4;

union U8 { uint4 u; short8 s; };

#if defined(__has_builtin)
#if __has_builtin(__builtin_amdgcn_global_load_lds)
#define HAVE_GLL 1
#endif
#endif

#ifdef HAVE_GLL
static __device__ __forceinline__ void STAGE16(const void* g, void* l) {
  __builtin_amdgcn_global_load_lds(
      (const __attribute__((address_space(1))) unsigned int*)g,
      (__attribute__((address_space(3))) unsigned int*)l, 16, 0, 0);
}
#else
static __device__ __forceinline__ void STAGE16(const void* g, void* l) {
  *(float4*)l = *(const float4*)g;
}
#endif

static __device__ __forceinline__ unsigned int pk2(float a, float b) {
  __hip_bfloat162 h = __float22bfloat162_rn(make_float2(a, b));
  union { __hip_bfloat162 h; unsigned int u; } c; c.h = h;
  return c.u;
}

// prep: 64 blocks = (h, batch-group of 8). Weights read once per block:
// fq (8 b x 64 d) in LDS, then v[b,h,k] packed bf16 B-fragments into vB.
__global__ __launch_bounds__(256) void prep(const float* __restrict__ qin,
    const float* __restrict__ Wq, const float* __restrict__ bq,
    const float* __restrict__ Wf, unsigned short* __restrict__ vB) {
  __shared__ float qs[8][DQ_];   // 16 KB
  __shared__ float fqs[8][D_];   // 2 KB
  int blk = blockIdx.x, h = blk >> 3, bg = blk & 7;
  int tid = threadIdx.x;
  int d = tid & 63, bp = tid >> 6;
#pragma unroll
  for (int bb = 0; bb < 8; ++bb) {
    qs[bb][tid] = qin[(size_t)(bg * 8 + bb) * DQ_ + tid];
    qs[bb][tid + 256] = qin[(size_t)(bg * 8 + bb) * DQ_ + tid + 256];
  }
  __syncthreads();
  {
    const float* w = Wq + (size_t)h * DQ_ * D_ + d;
    float a0 = 0.f, a1 = 0.f;
#pragma unroll 8
    for (int f = 0; f < DQ_; ++f) {
      float wv = w[(size_t)f * D_];
      a0 += qs[bp * 2][f] * wv;
      a1 += qs[bp * 2 + 1][f] * wv;
    }
    float bv = bq[h * D_ + d];
    fqs[bp * 2][d] = a0 + bv;
    fqs[bp * 2 + 1][d] = a1 + bv;
  }
  __syncthreads();
  // v: thread = k row of Wf[h]; 8 batches per thread
  const float4* wr = (const float4*)(Wf + (size_t)h * DF_ * D_ + (size_t)tid * D_);
  float acc[8] = {0.f, 0.f, 0.f, 0.f, 0.f, 0.f, 0.f, 0.f};
#pragma unroll
  for (int i = 0; i < 16; ++i) {
    float4 wv = wr[i];
#pragma unroll
    for (int bb = 0; bb < 8; ++bb) {
      float4 fv = ((const float4*)&fqs[bb][0])[i];
      acc[bb] += wv.x * fv.x + wv.y * fv.y + wv.z * fv.z + wv.w * fv.w;
    }
  }
  int ks = tid >> 5, kg = (tid >> 3) & 3, j = tid & 7;
#pragma unroll
  for (int bb = 0; bb < 8; ++bb) {
    size_t base = (size_t)(bg * 8 + bb) * 4096 + ks * 512;
    vB[base + (kg * 16 + h) * 8 + j] = (unsigned short)(pk2(acc[bb], 0.f) & 0xFFFF);
    vB[base + (kg * 16 + 8 + h) * 8 + j] = 0;
  }
}

// Main: 512 blocks x 4 waves, 1 block/CU. fact DMA-staged fp32 (padded +
// row-permuted rows), TRIPLE-buffered, 2 chunks in flight; raw s_barrier +
// counted vmcnt(9) (T3/T4) so prefetch spans barriers. Uniform 9 DMA
// instructions per wave per chunk (tail spread 8 lanes/wave).
__global__ __launch_bounds__(256, 1) void mha_main(
    const float* __restrict__ fact, const unsigned short* __restrict__ vB,
    float* __restrict__ part_s, float* __restrict__ part_ml) {
  __shared__ char buf[3 * BUFB];        // 99840 B
  __shared__ float4 exch[2][4][64];     // 8192 B

  const int tid = threadIdx.x;
  const int l = tid & 63, w = tid >> 6;
  const int dl = l & 15, kg = l >> 4;
  const int bid = blockIdx.x;
  const int b = bid >> 3, qq = bid & 7;

  short8 vfrag[2];
#pragma unroll
  for (int ks = 0; ks < 2; ++ks)
    vfrag[ks] = *(const short8*)(vB + (size_t)b * 4096 + (2 * w + ks) * 512 + l * 8);

  const float* factb = fact + ((size_t)b * T_ + (size_t)qq * 512) * DF_;

  // staging map: granule id -> LDS(row rho, slot); global row = pi^-1(rho)
  int srow[8], sslot[8];
#pragma unroll
  for (int i = 0; i < 8; ++i) {
    int id = i * 256 + tid;
    int rho = id / 65;
    int kgr = (rho >> 3) & 3;
    srow[i] = (rho & ~7) | (((rho & 7) + 8 - 2 * kgr) & 7);
    sslot[i] = id % 65;
  }
  const int id8 = 2048 + w * 8 + (l & 7);
  int srow8, sslot8;
  {
    int rho = id8 / 65;
    int kgr = (rho >> 3) & 3;
    srow8 = (rho & ~7) | (((rho & 7) + 8 - 2 * kgr) & 7);
    sslot8 = id8 % 65;
  }

  // A-side LDS rows (pi applied)
  const int t0 = dl, t1 = 16 + dl;
  const int lr0 = (t0 & ~7) | (((t0 & 7) + 2 * ((t0 >> 3) & 3)) & 7);
  const int lr1 = (t1 & ~7) | (((t1 & 7) + 2 * ((t1 >> 3) & 3)) & 7);
  const int aoff0 = lr0 * ROWB + (w * 64 + kg * 8) * 4;
  const int aoff1 = lr1 * ROWB + (w * 64 + kg * 8) * 4;
  // S-side row byte offsets (pi applied)
  int roff[8];
#pragma unroll
  for (int j = 0; j < 8; ++j)
    roff[j] = (kg * 8 + ((j + 2 * kg) & 7)) * ROWB;

#define ISSUE(C) {                                                            \
    const char* gsrc = (const char*)(factb + (size_t)(C) * CHUNK * DF_);      \
    char* ldst = buf + ((C) % 3) * BUFB;                                      \
    _Pragma("unroll") for (int i = 0; i < 8; ++i) {                           \
      int id = i * 256 + tid;                                                 \
      const void* sp = (sslot[i] < 64)                                        \
          ? (const void*)(gsrc + (size_t)srow[i] * 1024 + sslot[i] * 16)      \
          : (const void*)gsrc;                                                \
      STAGE16(sp, (void*)(ldst + id * 16));                                   \
    }                                                                         \
    if (l < 8) {                                                              \
      const void* sp = (sslot8 < 64)                                          \
          ? (const void*)(gsrc + (size_t)srow8 * 1024 + sslot8 * 16)          \
          : (const void*)gsrc;                                                \
      STAGE16(sp, (void*)(ldst + id8 * 16));                                  \
    } }

  float m_run = -INFINITY, l_part = 0.f;
  f32x4 acc_s[4];
#pragma unroll
  for (int n = 0; n < 4; ++n) { f32x4 z = {0.f, 0.f, 0.f, 0.f}; acc_s[n] = z; }

  ISSUE(0);
  ISSUE(1);

  for (int c = 0; c < NCH; ++c) {
    // top barrier: chunk c drained (c+1 stays in flight), raw barrier
    if (c == NCH - 1) { asm volatile("s_waitcnt vmcnt(0)" ::: "memory"); }
    else { asm volatile("s_waitcnt vmcnt(9)" ::: "memory"); }
    __builtin_amdgcn_sched_barrier(0);
    __builtin_amdgcn_s_barrier();
    __builtin_amdgcn_sched_barrier(0);

    const char* bc = buf + (c % 3) * BUFB;

    // ---- part 1: A-fragments + K=64 logit partials ----
    f32x4 dp[2];
#pragma unroll
    for (int t2 = 0; t2 < 2; ++t2) {
      const char* arow = bc + (t2 ? aoff1 : aoff0);
      float4 a0 = *(const float4*)arow;
      float4 a1 = *(const float4*)(arow + 16);
      float4 a2 = *(const float4*)(arow + 128);
      float4 a3 = *(const float4*)(arow + 144);
      U8 af0, af1;
      af0.u.x = pk2(a0.x, a0.y); af0.u.y = pk2(a0.z, a0.w);
      af0.u.z = pk2(a1.x, a1.y); af0.u.w = pk2(a1.z, a1.w);
      af1.u.x = pk2(a2.x, a2.y); af1.u.y = pk2(a2.z, a2.w);
      af1.u.z = pk2(a3.x, a3.y); af1.u.w = pk2(a3.z, a3.w);
      f32x4 d_ = {0.f, 0.f, 0.f, 0.f};
      d_ = __builtin_amdgcn_mfma_f32_16x16x32_bf16(af0.s, vfrag[0], d_, 0, 0, 0);
      d_ = __builtin_amdgcn_mfma_f32_16x16x32_bf16(af1.s, vfrag[1], d_, 0, 0, 0);
      dp[t2] = d_;
      exch[t2][w][l] = make_float4(d_[0], d_[1], d_[2], d_[3]);
    }
    // mid barrier: exch writes visible
    asm volatile("s_waitcnt lgkmcnt(0)" ::: "memory");
    __builtin_amdgcn_sched_barrier(0);
    __builtin_amdgcn_s_barrier();
    __builtin_amdgcn_sched_barrier(0);

    if (c + 2 < NCH) ISSUE(c + 2); // covered by softmax + S-phase + next part1

    f32x4 l0 = dp[0], l1 = dp[1];
#pragma unroll
    for (int ww = 1; ww < 4; ++ww) {
      int o = (w + ww) & 3;
      float4 p0 = exch[0][o][l], p1 = exch[1][o][l];
      l0[0] += p0.x; l0[1] += p0.y; l0[2] += p0.z; l0[3] += p0.w;
      l1[0] += p1.x; l1[1] += p1.y; l1[2] += p1.z; l1[3] += p1.w;
    }

    // ---- online softmax: lane(dl=h) rows t = kg*4+r (+16 for l1) ----
    float tmax = fmaxf(fmaxf(fmaxf(l0[0], l0[1]), fmaxf(l0[2], l0[3])),
                       fmaxf(fmaxf(l1[0], l1[1]), fmaxf(l1[2], l1[3])));
    tmax = fmaxf(tmax, __shfl_xor(tmax, 16));
    tmax = fmaxf(tmax, __shfl_xor(tmax, 32));
    int need = (tmax > m_run + 8.f) && (dl < 8);
    if (__any(need)) {
      float mnew = fmaxf(m_run, tmax);
      float f = __expf(m_run - mnew);
      m_run = mnew;
      l_part *= f;
      float f0 = __shfl(f, kg * 4 + 0), f1 = __shfl(f, kg * 4 + 1);
      float f2 = __shfl(f, kg * 4 + 2), f3 = __shfl(f, kg * 4 + 3);
      if (kg < 2) {
#pragma unroll
        for (int n = 0; n < 4; ++n) {
          acc_s[n][0] *= f0; acc_s[n][1] *= f1; acc_s[n][2] *= f2; acc_s[n][3] *= f3;
        }
      }
    }
    float e0 = __expf(l0[0] - m_run), e1 = __expf(l0[1] - m_run);
    float e2 = __expf(l0[2] - m_run), e3 = __expf(l0[3] - m_run);
    float e4 = __expf(l1[0] - m_run), e5 = __expf(l1[1] - m_run);
    float e6 = __expf(l1[2] - m_run), e7 = __expf(l1[3] - m_run);
    l_part += (e0 + e1 + e2 + e3) + (e4 + e5 + e6 + e7);

    unsigned int pk00 = pk2(e0, e1), pk01 = pk2(e2, e3);
    unsigned int pk10 = pk2(e4, e5), pk11 = pk2(e6, e7);
    if (dl == 8) { pk00 = pk01 = pk10 = pk11 = 0x3F803F80u; } // ones -> colsum

    int sa = dl + ((kg & 1) ? 32 : 0);
    int sb = sa + 16;
    unsigned int g00 = __shfl(pk00, sa), g01 = __shfl(pk01, sa);
    unsigned int g02 = __shfl(pk00, sb), g03 = __shfl(pk01, sb);
    unsigned int g10 = __shfl(pk10, sa), g11 = __shfl(pk11, sa);
    unsigned int g12 = __shfl(pk10, sb), g13 = __shfl(pk11, sb);
    U8 eA;
    eA.u.x = (kg < 2) ? g00 : g10;
    eA.u.y = (kg < 2) ? g01 : g11;
    eA.u.z = (kg < 2) ? g02 : g12;
    eA.u.w = (kg < 2) ? g03 : g13;

    // ---- S += e^T @ chunk; B-fragments via permuted column walk ----
#pragma unroll
    for (int n = 0; n < 4; ++n) {
      const char* srd = bc + (size_t)(w * 64 + n * 16 + dl) * 4;
      float b0 = *(const float*)(srd + roff[0]);
      float b1 = *(const float*)(srd + roff[1]);
      float b2 = *(const float*)(srd + roff[2]);
      float b3 = *(const float*)(srd + roff[3]);
      float b4 = *(const float*)(srd + roff[4]);
      float b5 = *(const float*)(srd + roff[5]);
      float b6 = *(const float*)(srd + roff[6]);
      float b7 = *(const float*)(srd + roff[7]);
      U8 bb;
      bb.u.x = pk2(b0, b1); bb.u.y = pk2(b2, b3);
      bb.u.z = pk2(b4, b5); bb.u.w = pk2(b6, b7);
      acc_s[n] = __builtin_amdgcn_mfma_f32_16x16x32_bf16(eA.s, bb.s, acc_s[n], 0, 0, 0);
    }
  }

  // ---- epilogue ----
  l_part += __shfl_xor(l_part, 16);
  l_part += __shfl_xor(l_part, 32);
  if (w == 0 && l < 8) {
    part_ml[(size_t)bid * 16 + l] = m_run;
    part_ml[(size_t)bid * 16 + 8 + l] = l_part;
  }
  float* ps = part_s + (size_t)bid * PS_STRIDE;
  if (kg < 2) {
#pragma unroll
    for (int n = 0; n < 4; ++n) {
      int f = w * 64 + n * 16 + dl;
      ps[(kg * 4 + 0) * 256 + f] = acc_s[n][0];
      ps[(kg * 4 + 1) * 256 + f] = acc_s[n][1];
      ps[(kg * 4 + 2) * 256 + f] = acc_s[n][2];
      ps[(kg * 4 + 3) * 256 + f] = acc_s[n][3];
    }
  } else if (kg == 2) {
#pragma unroll
    for (int n = 0; n < 4; ++n)
      ps[8 * 256 + w * 64 + n * 16 + dl] = acc_s[n][0]; // colsum row
  }
}

// combine 8 block-partials per (b,h); project through Wf[h]; add bias terms
__global__ __launch_bounds__(256) void reduce_k(const float* __restrict__ part_s,
    const float* __restrict__ part_ml, const float* __restrict__ Wf,
    const float* __restrict__ bf, float* __restrict__ out) {
  __shared__ float s_l[DF_];
  __shared__ float red[4][D_];
  int bh = blockIdx.x, b = bh >> 3, h = bh & 7;
  int tid = threadIdx.x, d = tid & 63, fc = tid >> 6;
  float M = -INFINITY;
  float mq[8];
#pragma unroll
  for (int q = 0; q < 8; ++q) {
    mq[q] = part_ml[(size_t)(b * 8 + q) * 16 + h];
    M = fmaxf(M, mq[q]);
  }
  float L = 0.f, sa = 0.f, cs = 0.f;
#pragma unroll
  for (int q = 0; q < 8; ++q) {
    float e = __expf(mq[q] - M);
    L += e * part_ml[(size_t)(b * 8 + q) * 16 + 8 + h];
    const float* ps = part_s + (size_t)(b * 8 + q) * PS_STRIDE;
    sa += e * ps[h * 256 + tid];
    cs += ps[8 * 256 + tid];
  }
  s_l[tid] = sa / L + EPS_ * cs;
  __syncthreads();
  const float* wbase = Wf + (size_t)h * DF_ * D_ + (size_t)fc * 64 * D_ + d;
  float o = 0.f;
#pragma unroll 8
  for (int k = 0; k < 64; ++k) o += s_l[fc * 64 + k] * wbase[(size_t)k * D_];
  red[fc][d] = o;
  __syncthreads();
  if (fc == 0)
    out[(size_t)b * (H_ * D_) + h * D_ + d] =
        o + red[1][d] + red[2][d] + red[3][d] + (1.f + (float)T_ * EPS_) * bf[h * D_ + d];
}

extern "C" void kernel_launch(void* const* d_in, const int* in_sizes, int n_in,
                              void* d_out, int out_size, void* d_ws, size_t ws_size,
                              hipStream_t stream) {
  const float* query = (const float*)d_in[0];
  const float* fact  = (const float*)d_in[1];
  const float* Wq    = (const float*)d_in[2];
  const float* bq    = (const float*)d_in[3];
  const float* Wf    = (const float*)d_in[4];
  const float* bf    = (const float*)d_in[5];
  float* out = (float*)d_out;

  char* ws = (char*)d_ws;
  unsigned short* vB = (unsigned short*)ws;                // 524288 B
  float* part_ml = (float*)(ws + 524288);                  // 32768 B
  float* part_s = (float*)(ws + 557056);                   // 4718592 B

  prep<<<dim3(64), dim3(256), 0, stream>>>(query, Wq, bq, Wf, vB);
  mha_main<<<dim3(NBLK), dim3(256), 0, stream>>>(fact, vB, part_s, part_ml);
  reduce_k<<<dim3(B_ * H_), dim3(256), 0, stream>>>(part_s, part_ml, Wf, bf, out);
}

// Round 9
// 89.774 us; speedup vs baseline: 1.0693x; 1.0693x over previous
//
#include <hip/hip_runtime.h>
#include <hip/hip_bf16.h>

#define B_ 64
#define T_ 4096
#define DQ_ 512
#define DF_ 256
#define H_ 8
#define D_ 64
#define EPS_ 1e-7f
#define NBLK 512        /* (b, qq): 8 blocks per batch, 512 rows each */
#define CHUNK 32        /* rows per staged chunk */
#define NCH 16          /* chunks per block */
#define PS_STRIDE 2304  /* per-block partial: 9 rows x 256 */
#define ROWB 1040       /* padded LDS row bytes (65 16B slots) */
#define SLOTS 2080      /* 32 rows x 65 slots (slot 64 = pad) */
#define BUFB (SLOTS * 16)

typedef __attribute__((ext_vector_type(8))) short short8;
typedef __attribute__((ext_vector_type(4))) float f32x4;

union U8 { uint4 u; short8 s; };

#if defined(__has_builtin)
#if __has_builtin(__builtin_amdgcn_global_load_lds)
#define HAVE_GLL 1
#endif
#endif

#ifdef HAVE_GLL
static __device__ __forceinline__ void STAGE16(const void* g, void* l) {
  __builtin_amdgcn_global_load_lds(
      (const __attribute__((address_space(1))) unsigned int*)g,
      (__attribute__((address_space(3))) unsigned int*)l, 16, 0, 0);
}
#else
static __device__ __forceinline__ void STAGE16(const void* g, void* l) {
  *(float4*)l = *(const float4*)g;
}
#endif

static __device__ __forceinline__ unsigned int pk2(float a, float b) {
  __hip_bfloat162 h = __float22bfloat162_rn(make_float2(a, b));
  union { __hip_bfloat162 h; unsigned int u; } c; c.h = h;
  return c.u;
}

// prep: 64 blocks = (h, batch-group of 8). Weights read once per block:
// fq (8 b x 64 d) in LDS, then v[b,h,k] packed bf16 B-fragments into vB.
__global__ __launch_bounds__(256) void prep(const float* __restrict__ qin,
    const float* __restrict__ Wq, const float* __restrict__ bq,
    const float* __restrict__ Wf, unsigned short* __restrict__ vB) {
  __shared__ float qs[8][DQ_];   // 16 KB
  __shared__ float fqs[8][D_];   // 2 KB
  int blk = blockIdx.x, h = blk >> 3, bg = blk & 7;
  int tid = threadIdx.x;
  int d = tid & 63, bp = tid >> 6;
#pragma unroll
  for (int bb = 0; bb < 8; ++bb) {
    qs[bb][tid] = qin[(size_t)(bg * 8 + bb) * DQ_ + tid];
    qs[bb][tid + 256] = qin[(size_t)(bg * 8 + bb) * DQ_ + tid + 256];
  }
  __syncthreads();
  {
    const float* w = Wq + (size_t)h * DQ_ * D_ + d;
    float a0 = 0.f, a1 = 0.f;
#pragma unroll 8
    for (int f = 0; f < DQ_; ++f) {
      float wv = w[(size_t)f * D_];
      a0 += qs[bp * 2][f] * wv;
      a1 += qs[bp * 2 + 1][f] * wv;
    }
    float bv = bq[h * D_ + d];
    fqs[bp * 2][d] = a0 + bv;
    fqs[bp * 2 + 1][d] = a1 + bv;
  }
  __syncthreads();
  // v: thread = k row of Wf[h]; 8 batches per thread
  const float4* wr = (const float4*)(Wf + (size_t)h * DF_ * D_ + (size_t)tid * D_);
  float acc[8] = {0.f, 0.f, 0.f, 0.f, 0.f, 0.f, 0.f, 0.f};
#pragma unroll
  for (int i = 0; i < 16; ++i) {
    float4 wv = wr[i];
#pragma unroll
    for (int bb = 0; bb < 8; ++bb) {
      float4 fv = ((const float4*)&fqs[bb][0])[i];
      acc[bb] += wv.x * fv.x + wv.y * fv.y + wv.z * fv.z + wv.w * fv.w;
    }
  }
  int ks = tid >> 5, kg = (tid >> 3) & 3, j = tid & 7;
#pragma unroll
  for (int bb = 0; bb < 8; ++bb) {
    size_t base = (size_t)(bg * 8 + bb) * 4096 + ks * 512;
    vB[base + (kg * 16 + h) * 8 + j] = (unsigned short)(pk2(acc[bb], 0.f) & 0xFFFF);
    vB[base + (kg * 16 + 8 + h) * 8 + j] = 0;
  }
}

// Main: 512 blocks x 4 waves, 2 blocks/CU. fact DMA-staged fp32 (padded +
// row-permuted), double-buffered. ONE __syncthreads per chunk; each wave
// computes full K=256 logits itself (no exchange, no mid barrier), so the
// next chunk's DMA (issued right after the barrier) is covered by the whole
// iteration while the co-resident block fills residual drain gaps.
__global__ __launch_bounds__(256, 2) void mha_main(
    const float* __restrict__ fact, const unsigned short* __restrict__ vB,
    float* __restrict__ part_s, float* __restrict__ part_ml) {
  __shared__ char buf[2 * BUFB];        // 66560 B

  const int tid = threadIdx.x;
  const int l = tid & 63, w = tid >> 6;
  const int dl = l & 15, kg = l >> 4;
  const int bid = blockIdx.x;
  const int b = bid >> 3, qq = bid & 7;

  // full-K v B-fragments (all 256 features)
  short8 vfrag[8];
#pragma unroll
  for (int ks = 0; ks < 8; ++ks)
    vfrag[ks] = *(const short8*)(vB + (size_t)b * 4096 + ks * 512 + l * 8);

  const float* factb = fact + ((size_t)b * T_ + (size_t)qq * 512) * DF_;

  // staging map: granule id -> LDS(row rho, slot); global row = pi^-1(rho)
  int srow[9], sslot[9];
#pragma unroll
  for (int i = 0; i < 9; ++i) {
    int id = i * 256 + tid;
    int rho = id / 65;
    int kgr = (rho >> 3) & 3;
    srow[i] = (rho & ~7) | (((rho & 7) + 8 - 2 * kgr) & 7);
    sslot[i] = id % 65;
  }

  // A-side LDS rows (pi applied); full-K read base (kg slice only)
  const int t0 = dl, t1 = 16 + dl;
  const int lr0 = (t0 & ~7) | (((t0 & 7) + 2 * ((t0 >> 3) & 3)) & 7);
  const int lr1 = (t1 & ~7) | (((t1 & 7) + 2 * ((t1 >> 3) & 3)) & 7);
  const int aoff0 = lr0 * ROWB + kg * 32;
  const int aoff1 = lr1 * ROWB + kg * 32;
  // S-side row byte offsets (pi applied)
  int roff[8];
#pragma unroll
  for (int j = 0; j < 8; ++j)
    roff[j] = (kg * 8 + ((j + 2 * kg) & 7)) * ROWB;

#define ISSUE(C) {                                                            \
    const char* gsrc = (const char*)(factb + (size_t)(C) * CHUNK * DF_);      \
    char* ldst = buf + ((C) & 1) * BUFB;                                      \
    _Pragma("unroll") for (int i = 0; i < 9; ++i) {                           \
      int id = i * 256 + tid;                                                 \
      if (i < 8 || id < SLOTS) {                                              \
        const void* sp = (sslot[i] < 64)                                      \
            ? (const void*)(gsrc + (size_t)srow[i] * 1024 + sslot[i] * 16)    \
            : (const void*)gsrc;                                              \
        STAGE16(sp, (void*)(ldst + id * 16));                                 \
      } } }

  float m_run = -INFINITY, l_part = 0.f;
  f32x4 acc_s[4];
#pragma unroll
  for (int n = 0; n < 4; ++n) { f32x4 z = {0.f, 0.f, 0.f, 0.f}; acc_s[n] = z; }

  ISSUE(0);

  for (int c = 0; c < NCH; ++c) {
    __syncthreads(); // drains chunk c DMA; all waves done reading buf[(c+1)&1]
    if (c + 1 < NCH) ISSUE(c + 1); // covered by the ENTIRE iteration below

    const char* bc = buf + (c & 1) * BUFB;

    // ---- part 1: full K=256 logits per wave (no exchange) ----
    f32x4 dp[2];
#pragma unroll
    for (int t2 = 0; t2 < 2; ++t2) {
      const char* arow = bc + (t2 ? aoff1 : aoff0);
      f32x4 d_ = {0.f, 0.f, 0.f, 0.f};
#pragma unroll
      for (int ks = 0; ks < 8; ++ks) {
        float4 a0 = *(const float4*)(arow + ks * 128);
        float4 a1 = *(const float4*)(arow + ks * 128 + 16);
        U8 af;
        af.u.x = pk2(a0.x, a0.y); af.u.y = pk2(a0.z, a0.w);
        af.u.z = pk2(a1.x, a1.y); af.u.w = pk2(a1.z, a1.w);
        d_ = __builtin_amdgcn_mfma_f32_16x16x32_bf16(af.s, vfrag[ks], d_, 0, 0, 0);
      }
      dp[t2] = d_;
    }
    f32x4 l0 = dp[0], l1 = dp[1];

    // ---- online softmax: lane(dl=h) rows t = kg*4+r (+16 for l1) ----
    float tmax = fmaxf(fmaxf(fmaxf(l0[0], l0[1]), fmaxf(l0[2], l0[3])),
                       fmaxf(fmaxf(l1[0], l1[1]), fmaxf(l1[2], l1[3])));
    tmax = fmaxf(tmax, __shfl_xor(tmax, 16));
    tmax = fmaxf(tmax, __shfl_xor(tmax, 32));
    int need = (tmax > m_run + 8.f) && (dl < 8);
    if (__any(need)) {
      float mnew = fmaxf(m_run, tmax);
      float f = __expf(m_run - mnew);
      m_run = mnew;
      l_part *= f;
      float f0 = __shfl(f, kg * 4 + 0), f1 = __shfl(f, kg * 4 + 1);
      float f2 = __shfl(f, kg * 4 + 2), f3 = __shfl(f, kg * 4 + 3);
      if (kg < 2) {
#pragma unroll
        for (int n = 0; n < 4; ++n) {
          acc_s[n][0] *= f0; acc_s[n][1] *= f1; acc_s[n][2] *= f2; acc_s[n][3] *= f3;
        }
      }
    }
    float e0 = __expf(l0[0] - m_run), e1 = __expf(l0[1] - m_run);
    float e2 = __expf(l0[2] - m_run), e3 = __expf(l0[3] - m_run);
    float e4 = __expf(l1[0] - m_run), e5 = __expf(l1[1] - m_run);
    float e6 = __expf(l1[2] - m_run), e7 = __expf(l1[3] - m_run);
    l_part += (e0 + e1 + e2 + e3) + (e4 + e5 + e6 + e7);

    unsigned int pk00 = pk2(e0, e1), pk01 = pk2(e2, e3);
    unsigned int pk10 = pk2(e4, e5), pk11 = pk2(e6, e7);
    if (dl == 8) { pk00 = pk01 = pk10 = pk11 = 0x3F803F80u; } // ones -> colsum

    int sa = dl + ((kg & 1) ? 32 : 0);
    int sb = sa + 16;
    unsigned int g00 = __shfl(pk00, sa), g01 = __shfl(pk01, sa);
    unsigned int g02 = __shfl(pk00, sb), g03 = __shfl(pk01, sb);
    unsigned int g10 = __shfl(pk10, sa), g11 = __shfl(pk11, sa);
    unsigned int g12 = __shfl(pk10, sb), g13 = __shfl(pk11, sb);
    U8 eA;
    eA.u.x = (kg < 2) ? g00 : g10;
    eA.u.y = (kg < 2) ? g01 : g11;
    eA.u.z = (kg < 2) ? g02 : g12;
    eA.u.w = (kg < 2) ? g03 : g13;

    // ---- S += e^T @ chunk; B-fragments via permuted column walk ----
#pragma unroll
    for (int n = 0; n < 4; ++n) {
      const char* srd = bc + (size_t)(w * 64 + n * 16 + dl) * 4;
      float b0 = *(const float*)(srd + roff[0]);
      float b1 = *(const float*)(srd + roff[1]);
      float b2 = *(const float*)(srd + roff[2]);
      float b3 = *(const float*)(srd + roff[3]);
      float b4 = *(const float*)(srd + roff[4]);
      float b5 = *(const float*)(srd + roff[5]);
      float b6 = *(const float*)(srd + roff[6]);
      float b7 = *(const float*)(srd + roff[7]);
      U8 bb;
      bb.u.x = pk2(b0, b1); bb.u.y = pk2(b2, b3);
      bb.u.z = pk2(b4, b5); bb.u.w = pk2(b6, b7);
      acc_s[n] = __builtin_amdgcn_mfma_f32_16x16x32_bf16(eA.s, bb.s, acc_s[n], 0, 0, 0);
    }
  }

  // ---- epilogue (logits identical across waves -> w==0 writes m/l) ----
  l_part += __shfl_xor(l_part, 16);
  l_part += __shfl_xor(l_part, 32);
  if (w == 0 && l < 8) {
    part_ml[(size_t)bid * 16 + l] = m_run;
    part_ml[(size_t)bid * 16 + 8 + l] = l_part;
  }
  float* ps = part_s + (size_t)bid * PS_STRIDE;
  if (kg < 2) {
#pragma unroll
    for (int n = 0; n < 4; ++n) {
      int f = w * 64 + n * 16 + dl;
      ps[(kg * 4 + 0) * 256 + f] = acc_s[n][0];
      ps[(kg * 4 + 1) * 256 + f] = acc_s[n][1];
      ps[(kg * 4 + 2) * 256 + f] = acc_s[n][2];
      ps[(kg * 4 + 3) * 256 + f] = acc_s[n][3];
    }
  } else if (kg == 2) {
#pragma unroll
    for (int n = 0; n < 4; ++n)
      ps[8 * 256 + w * 64 + n * 16 + dl] = acc_s[n][0]; // colsum row
  }
}

// combine 8 block-partials per (b,h); project through Wf[h]; add bias terms
__global__ __launch_bounds__(256) void reduce_k(const float* __restrict__ part_s,
    const float* __restrict__ part_ml, const float* __restrict__ Wf,
    const float* __restrict__ bf, float* __restrict__ out) {
  __shared__ float s_l[DF_];
  __shared__ float red[4][D_];
  int bh = blockIdx.x, b = bh >> 3, h = bh & 7;
  int tid = threadIdx.x, d = tid & 63, fc = tid >> 6;
  float M = -INFINITY;
  float mq[8];
#pragma unroll
  for (int q = 0; q < 8; ++q) {
    mq[q] = part_ml[(size_t)(b * 8 + q) * 16 + h];
    M = fmaxf(M, mq[q]);
  }
  float L = 0.f, sa = 0.f, cs = 0.f;
#pragma unroll
  for (int q = 0; q < 8; ++q) {
    float e = __expf(mq[q] - M);
    L += e * part_ml[(size_t)(b * 8 + q) * 16 + 8 + h];
    const float* ps = part_s + (size_t)(b * 8 + q) * PS_STRIDE;
    sa += e * ps[h * 256 + tid];
    cs += ps[8 * 256 + tid];
  }
  s_l[tid] = sa / L + EPS_ * cs;
  __syncthreads();
  const float* wbase = Wf + (size_t)h * DF_ * D_ + (size_t)fc * 64 * D_ + d;
  float o = 0.f;
#pragma unroll 8
  for (int k = 0; k < 64; ++k) o += s_l[fc * 64 + k] * wbase[(size_t)k * D_];
  red[fc][d] = o;
  __syncthreads();
  if (fc == 0)
    out[(size_t)b * (H_ * D_) + h * D_ + d] =
        o + red[1][d] + red[2][d] + red[3][d] + (1.f + (float)T_ * EPS_) * bf[h * D_ + d];
}

extern "C" void kernel_launch(void* const* d_in, const int* in_sizes, int n_in,
                              void* d_out, int out_size, void* d_ws, size_t ws_size,
                              hipStream_t stream) {
  const float* query = (const float*)d_in[0];
  const float* fact  = (const float*)d_in[1];
  const float* Wq    = (const float*)d_in[2];
  const float* bq    = (const float*)d_in[3];
  const float* Wf    = (const float*)d_in[4];
  const float* bf    = (const float*)d_in[5];
  float* out = (float*)d_out;

  char* ws = (char*)d_ws;
  unsigned short* vB = (unsigned short*)ws;                // 524288 B
  float* part_ml = (float*)(ws + 524288);                  // 32768 B
  float* part_s = (float*)(ws + 557056);                   // 4718592 B

  prep<<<dim3(64), dim3(256), 0, stream>>>(query, Wq, bq, Wf, vB);
  mha_main<<<dim3(NBLK), dim3(256), 0, stream>>>(fact, vB, part_s, part_ml);
  reduce_k<<<dim3(B_ * H_), dim3(256), 0, stream>>>(part_s, part_ml, Wf, bf, out);
}

// Round 10
// 81.216 us; speedup vs baseline: 1.1820x; 1.1054x over previous
//
#include <hip/hip_runtime.h>
#include <hip/hip_bf16.h>

#define B_ 64
#define T_ 4096
#define DQ_ 512
#define DF_ 256
#define H_ 8
#define D_ 64
#define EPS_ 1e-7f
#define NBLK 512        /* (b, qq): 8 blocks per batch, 512 rows each */
#define CHUNK 32        /* rows per staged chunk */
#define NCH 16          /* chunks per block */
#define PS_STRIDE 2304  /* per-block partial: 9 rows x 256 */
#define ROWB 1040       /* padded LDS row bytes (65 16B slots) */
#define SLOTS 2080      /* 32 rows x 65 slots (slot 64 = pad) */
#define BUFB (SLOTS * 16)

typedef __attribute__((ext_vector_type(8))) short short8;
typedef __attribute__((ext_vector_type(4))) float f32x4;

union U8 { uint4 u; short8 s; };

#if defined(__has_builtin)
#if __has_builtin(__builtin_amdgcn_global_load_lds)
#define HAVE_GLL 1
#endif
#endif

#ifdef HAVE_GLL
static __device__ __forceinline__ void STAGE16(const void* g, void* l) {
  __builtin_amdgcn_global_load_lds(
      (const __attribute__((address_space(1))) unsigned int*)g,
      (__attribute__((address_space(3))) unsigned int*)l, 16, 0, 0);
}
#else
static __device__ __forceinline__ void STAGE16(const void* g, void* l) {
  *(float4*)l = *(const float4*)g;
}
#endif

static __device__ __forceinline__ unsigned int pk2(float a, float b) {
  __hip_bfloat162 h = __float22bfloat162_rn(make_float2(a, b));
  union { __hip_bfloat162 h; unsigned int u; } c; c.h = h;
  return c.u;
}

// prep: 64 blocks = (h, batch-group of 8). Weights read once per block:
// fq (8 b x 64 d) in LDS, then v[b,h,k] packed bf16 B-fragments into vB.
__global__ __launch_bounds__(256) void prep(const float* __restrict__ qin,
    const float* __restrict__ Wq, const float* __restrict__ bq,
    const float* __restrict__ Wf, unsigned short* __restrict__ vB) {
  __shared__ float qs[8][DQ_];   // 16 KB
  __shared__ float fqs[8][D_];   // 2 KB
  int blk = blockIdx.x, h = blk >> 3, bg = blk & 7;
  int tid = threadIdx.x;
  int d = tid & 63, bp = tid >> 6;
#pragma unroll
  for (int bb = 0; bb < 8; ++bb) {
    qs[bb][tid] = qin[(size_t)(bg * 8 + bb) * DQ_ + tid];
    qs[bb][tid + 256] = qin[(size_t)(bg * 8 + bb) * DQ_ + tid + 256];
  }
  __syncthreads();
  {
    const float* w = Wq + (size_t)h * DQ_ * D_ + d;
    float a0 = 0.f, a1 = 0.f;
#pragma unroll 8
    for (int f = 0; f < DQ_; ++f) {
      float wv = w[(size_t)f * D_];
      a0 += qs[bp * 2][f] * wv;
      a1 += qs[bp * 2 + 1][f] * wv;
    }
    float bv = bq[h * D_ + d];
    fqs[bp * 2][d] = a0 + bv;
    fqs[bp * 2 + 1][d] = a1 + bv;
  }
  __syncthreads();
  // v: thread = k row of Wf[h]; 8 batches per thread
  const float4* wr = (const float4*)(Wf + (size_t)h * DF_ * D_ + (size_t)tid * D_);
  float acc[8] = {0.f, 0.f, 0.f, 0.f, 0.f, 0.f, 0.f, 0.f};
#pragma unroll
  for (int i = 0; i < 16; ++i) {
    float4 wv = wr[i];
#pragma unroll
    for (int bb = 0; bb < 8; ++bb) {
      float4 fv = ((const float4*)&fqs[bb][0])[i];
      acc[bb] += wv.x * fv.x + wv.y * fv.y + wv.z * fv.z + wv.w * fv.w;
    }
  }
  int ks = tid >> 5, kg = (tid >> 3) & 3, j = tid & 7;
#pragma unroll
  for (int bb = 0; bb < 8; ++bb) {
    size_t base = (size_t)(bg * 8 + bb) * 4096 + ks * 512;
    vB[base + (kg * 16 + h) * 8 + j] = (unsigned short)(pk2(acc[bb], 0.f) & 0xFFFF);
    vB[base + (kg * 16 + 8 + h) * 8 + j] = 0;
  }
}

// Main: r7 structure (512 blocks x 4 waves, 2 blocks/CU, double buffer,
// split-K logits + LDS exchange) with two changes:
//  - mid barrier = raw s_barrier + lgkmcnt(0) (no vmcnt drain)
//  - ISSUE(c+1) right after the top barrier -> DMA covered by whole iteration
__global__ __launch_bounds__(256, 2) void mha_main(
    const float* __restrict__ fact, const unsigned short* __restrict__ vB,
    float* __restrict__ part_s, float* __restrict__ part_ml) {
  __shared__ char buf[2 * BUFB];        // 66560 B
  __shared__ float4 exch[2][4][64];     // 8192 B

  const int tid = threadIdx.x;
  const int l = tid & 63, w = tid >> 6;
  const int dl = l & 15, kg = l >> 4;
  const int bid = blockIdx.x;
  const int b = bid >> 3, qq = bid & 7;

  // this wave's 64-feature slice of the v B-fragments
  short8 vfrag[2];
#pragma unroll
  for (int ks = 0; ks < 2; ++ks)
    vfrag[ks] = *(const short8*)(vB + (size_t)b * 4096 + (2 * w + ks) * 512 + l * 8);

  const float* factb = fact + ((size_t)b * T_ + (size_t)qq * 512) * DF_;

  // staging map: granule id -> LDS(row rho, slot); global row = pi^-1(rho)
  int srow[9], sslot[9];
#pragma unroll
  for (int i = 0; i < 9; ++i) {
    int id = i * 256 + tid;
    int rho = id / 65;
    int kgr = (rho >> 3) & 3;
    srow[i] = (rho & ~7) | (((rho & 7) + 8 - 2 * kgr) & 7);
    sslot[i] = id % 65;
  }

  // A-side LDS rows (pi applied)
  const int t0 = dl, t1 = 16 + dl;
  const int lr0 = (t0 & ~7) | (((t0 & 7) + 2 * ((t0 >> 3) & 3)) & 7);
  const int lr1 = (t1 & ~7) | (((t1 & 7) + 2 * ((t1 >> 3) & 3)) & 7);
  const int aoff0 = lr0 * ROWB + (w * 64 + kg * 8) * 4;
  const int aoff1 = lr1 * ROWB + (w * 64 + kg * 8) * 4;
  // S-side row byte offsets (pi applied)
  int roff[8];
#pragma unroll
  for (int j = 0; j < 8; ++j)
    roff[j] = (kg * 8 + ((j + 2 * kg) & 7)) * ROWB;

#define ISSUE(C) {                                                            \
    const char* gsrc = (const char*)(factb + (size_t)(C) * CHUNK * DF_);      \
    char* ldst = buf + ((C) & 1) * BUFB;                                      \
    _Pragma("unroll") for (int i = 0; i < 9; ++i) {                           \
      int id = i * 256 + tid;                                                 \
      if (i < 8 || id < SLOTS) {                                              \
        const void* sp = (sslot[i] < 64)                                      \
            ? (const void*)(gsrc + (size_t)srow[i] * 1024 + sslot[i] * 16)    \
            : (const void*)gsrc;                                              \
        STAGE16(sp, (void*)(ldst + id * 16));                                 \
      } } }

  float m_run = -INFINITY, l_part = 0.f;
  f32x4 acc_s[4];
#pragma unroll
  for (int n = 0; n < 4; ++n) { f32x4 z = {0.f, 0.f, 0.f, 0.f}; acc_s[n] = z; }

  ISSUE(0);

  for (int c = 0; c < NCH; ++c) {
    __syncthreads(); // drains chunk c DMA; buf[(c+1)&1] reads (iter c-1) sealed
    if (c + 1 < NCH) ISSUE(c + 1); // in flight across the ENTIRE iteration

    const char* bc = buf + (c & 1) * BUFB;

    // ---- part 1: per-tile A-fragments + K=64 logit partials ----
    f32x4 dp[2];
#pragma unroll
    for (int t2 = 0; t2 < 2; ++t2) {
      const char* arow = bc + (t2 ? aoff1 : aoff0);
      float4 a0 = *(const float4*)arow;
      float4 a1 = *(const float4*)(arow + 16);
      float4 a2 = *(const float4*)(arow + 128);
      float4 a3 = *(const float4*)(arow + 144);
      U8 af0, af1;
      af0.u.x = pk2(a0.x, a0.y); af0.u.y = pk2(a0.z, a0.w);
      af0.u.z = pk2(a1.x, a1.y); af0.u.w = pk2(a1.z, a1.w);
      af1.u.x = pk2(a2.x, a2.y); af1.u.y = pk2(a2.z, a2.w);
      af1.u.z = pk2(a3.x, a3.y); af1.u.w = pk2(a3.z, a3.w);
      f32x4 d_ = {0.f, 0.f, 0.f, 0.f};
      d_ = __builtin_amdgcn_mfma_f32_16x16x32_bf16(af0.s, vfrag[0], d_, 0, 0, 0);
      d_ = __builtin_amdgcn_mfma_f32_16x16x32_bf16(af1.s, vfrag[1], d_, 0, 0, 0);
      dp[t2] = d_;
      exch[t2][w][l] = make_float4(d_[0], d_[1], d_[2], d_[3]);
    }
    // mid barrier: raw s_barrier + lgkmcnt only -> chunk c+1 DMA stays in flight
    asm volatile("s_waitcnt lgkmcnt(0)" ::: "memory");
    __builtin_amdgcn_sched_barrier(0);
    __builtin_amdgcn_s_barrier();
    __builtin_amdgcn_sched_barrier(0);

    f32x4 l0 = dp[0], l1 = dp[1];
#pragma unroll
    for (int ww = 1; ww < 4; ++ww) {
      int o = (w + ww) & 3;
      float4 p0 = exch[0][o][l], p1 = exch[1][o][l];
      l0[0] += p0.x; l0[1] += p0.y; l0[2] += p0.z; l0[3] += p0.w;
      l1[0] += p1.x; l1[1] += p1.y; l1[2] += p1.z; l1[3] += p1.w;
    }

    // ---- online softmax: lane(dl=h) rows t = kg*4+r (+16 for l1) ----
    float tmax = fmaxf(fmaxf(fmaxf(l0[0], l0[1]), fmaxf(l0[2], l0[3])),
                       fmaxf(fmaxf(l1[0], l1[1]), fmaxf(l1[2], l1[3])));
    tmax = fmaxf(tmax, __shfl_xor(tmax, 16));
    tmax = fmaxf(tmax, __shfl_xor(tmax, 32));
    int need = (tmax > m_run + 8.f) && (dl < 8);
    if (__any(need)) {
      float mnew = fmaxf(m_run, tmax);
      float f = __expf(m_run - mnew);
      m_run = mnew;
      l_part *= f;
      float f0 = __shfl(f, kg * 4 + 0), f1 = __shfl(f, kg * 4 + 1);
      float f2 = __shfl(f, kg * 4 + 2), f3 = __shfl(f, kg * 4 + 3);
      if (kg < 2) {
#pragma unroll
        for (int n = 0; n < 4; ++n) {
          acc_s[n][0] *= f0; acc_s[n][1] *= f1; acc_s[n][2] *= f2; acc_s[n][3] *= f3;
        }
      }
    }
    float e0 = __expf(l0[0] - m_run), e1 = __expf(l0[1] - m_run);
    float e2 = __expf(l0[2] - m_run), e3 = __expf(l0[3] - m_run);
    float e4 = __expf(l1[0] - m_run), e5 = __expf(l1[1] - m_run);
    float e6 = __expf(l1[2] - m_run), e7 = __expf(l1[3] - m_run);
    l_part += (e0 + e1 + e2 + e3) + (e4 + e5 + e6 + e7);

    unsigned int pk00 = pk2(e0, e1), pk01 = pk2(e2, e3);
    unsigned int pk10 = pk2(e4, e5), pk11 = pk2(e6, e7);
    if (dl == 8) { pk00 = pk01 = pk10 = pk11 = 0x3F803F80u; } // ones -> colsum

    int sa = dl + ((kg & 1) ? 32 : 0);
    int sb = sa + 16;
    unsigned int g00 = __shfl(pk00, sa), g01 = __shfl(pk01, sa);
    unsigned int g02 = __shfl(pk00, sb), g03 = __shfl(pk01, sb);
    unsigned int g10 = __shfl(pk10, sa), g11 = __shfl(pk11, sa);
    unsigned int g12 = __shfl(pk10, sb), g13 = __shfl(pk11, sb);
    U8 eA;
    eA.u.x = (kg < 2) ? g00 : g10;
    eA.u.y = (kg < 2) ? g01 : g11;
    eA.u.z = (kg < 2) ? g02 : g12;
    eA.u.w = (kg < 2) ? g03 : g13;

    // ---- S += e^T @ chunk; B-fragments via permuted column walk ----
#pragma unroll
    for (int n = 0; n < 4; ++n) {
      const char* srd = bc + (size_t)(w * 64 + n * 16 + dl) * 4;
      float b0 = *(const float*)(srd + roff[0]);
      float b1 = *(const float*)(srd + roff[1]);
      float b2 = *(const float*)(srd + roff[2]);
      float b3 = *(const float*)(srd + roff[3]);
      float b4 = *(const float*)(srd + roff[4]);
      float b5 = *(const float*)(srd + roff[5]);
      float b6 = *(const float*)(srd + roff[6]);
      float b7 = *(const float*)(srd + roff[7]);
      U8 bb;
      bb.u.x = pk2(b0, b1); bb.u.y = pk2(b2, b3);
      bb.u.z = pk2(b4, b5); bb.u.w = pk2(b6, b7);
      acc_s[n] = __builtin_amdgcn_mfma_f32_16x16x32_bf16(eA.s, bb.s, acc_s[n], 0, 0, 0);
    }
  }

  // ---- epilogue ----
  l_part += __shfl_xor(l_part, 16);
  l_part += __shfl_xor(l_part, 32);
  if (w == 0 && l < 8) {
    part_ml[(size_t)bid * 16 + l] = m_run;
    part_ml[(size_t)bid * 16 + 8 + l] = l_part;
  }
  float* ps = part_s + (size_t)bid * PS_STRIDE;
  if (kg < 2) {
#pragma unroll
    for (int n = 0; n < 4; ++n) {
      int f = w * 64 + n * 16 + dl;
      ps[(kg * 4 + 0) * 256 + f] = acc_s[n][0];
      ps[(kg * 4 + 1) * 256 + f] = acc_s[n][1];
      ps[(kg * 4 + 2) * 256 + f] = acc_s[n][2];
      ps[(kg * 4 + 3) * 256 + f] = acc_s[n][3];
    }
  } else if (kg == 2) {
#pragma unroll
    for (int n = 0; n < 4; ++n)
      ps[8 * 256 + w * 64 + n * 16 + dl] = acc_s[n][0]; // colsum row
  }
}

// combine 8 block-partials per (b,h); project through Wf[h]; add bias terms
__global__ __launch_bounds__(256) void reduce_k(const float* __restrict__ part_s,
    const float* __restrict__ part_ml, const float* __restrict__ Wf,
    const float* __restrict__ bf, float* __restrict__ out) {
  __shared__ float s_l[DF_];
  __shared__ float red[4][D_];
  int bh = blockIdx.x, b = bh >> 3, h = bh & 7;
  int tid = threadIdx.x, d = tid & 63, fc = tid >> 6;
  float M = -INFINITY;
  float mq[8];
#pragma unroll
  for (int q = 0; q < 8; ++q) {
    mq[q] = part_ml[(size_t)(b * 8 + q) * 16 + h];
    M = fmaxf(M, mq[q]);
  }
  float L = 0.f, sa = 0.f, cs = 0.f;
#pragma unroll
  for (int q = 0; q < 8; ++q) {
    float e = __expf(mq[q] - M);
    L += e * part_ml[(size_t)(b * 8 + q) * 16 + 8 + h];
    const float* ps = part_s + (size_t)(b * 8 + q) * PS_STRIDE;
    sa += e * ps[h * 256 + tid];
    cs += ps[8 * 256 + tid];
  }
  s_l[tid] = sa / L + EPS_ * cs;
  __syncthreads();
  const float* wbase = Wf + (size_t)h * DF_ * D_ + (size_t)fc * 64 * D_ + d;
  float o = 0.f;
#pragma unroll 8
  for (int k = 0; k < 64; ++k) o += s_l[fc * 64 + k] * wbase[(size_t)k * D_];
  red[fc][d] = o;
  __syncthreads();
  if (fc == 0)
    out[(size_t)b * (H_ * D_) + h * D_ + d] =
        o + red[1][d] + red[2][d] + red[3][d] + (1.f + (float)T_ * EPS_) * bf[h * D_ + d];
}

extern "C" void kernel_launch(void* const* d_in, const int* in_sizes, int n_in,
                              void* d_out, int out_size, void* d_ws, size_t ws_size,
                              hipStream_t stream) {
  const float* query = (const float*)d_in[0];
  const float* fact  = (const float*)d_in[1];
  const float* Wq    = (const float*)d_in[2];
  const float* bq    = (const float*)d_in[3];
  const float* Wf    = (const float*)d_in[4];
  const float* bf    = (const float*)d_in[5];
  float* out = (float*)d_out;

  char* ws = (char*)d_ws;
  unsigned short* vB = (unsigned short*)ws;                // 524288 B
  float* part_ml = (float*)(ws + 524288);                  // 32768 B
  float* part_s = (float*)(ws + 557056);                   // 4718592 B

  prep<<<dim3(64), dim3(256), 0, stream>>>(query, Wq, bq, Wf, vB);
  mha_main<<<dim3(NBLK), dim3(256), 0, stream>>>(fact, vB, part_s, part_ml);
  reduce_k<<<dim3(B_ * H_), dim3(256), 0, stream>>>(part_s, part_ml, Wf, bf, out);
}

// Round 11
// 68.406 us; speedup vs baseline: 1.4033x; 1.1873x over previous
//
#include <hip/hip_runtime.h>
#include <hip/hip_bf16.h>

#define B_ 64
#define T_ 4096
#define DQ_ 512
#define DF_ 256
#define H_ 8
#define D_ 64
#define EPS_ 1e-7f
#define NBLK 512        /* (b, qq): 8 blocks per batch, 512 rows each */
#define CHUNK 32        /* rows per staged chunk */
#define NCH 16          /* chunks per block */
#define PS_STRIDE 2304  /* per-block partial: 9 rows x 256 */
#define ROWB 1040       /* padded LDS row bytes (65 16B slots) */
#define SLOTS 2080      /* 32 rows x 65 slots (slot 64 = pad) */
#define BUFB (SLOTS * 16)

typedef __attribute__((ext_vector_type(8))) short short8;
typedef __attribute__((ext_vector_type(4))) float f32x4;

union U8 { uint4 u; short8 s; };

#if defined(__has_builtin)
#if __has_builtin(__builtin_amdgcn_global_load_lds)
#define HAVE_GLL 1
#endif
#endif

#ifdef HAVE_GLL
static __device__ __forceinline__ void STAGE16(const void* g, void* l) {
  __builtin_amdgcn_global_load_lds(
      (const __attribute__((address_space(1))) unsigned int*)g,
      (__attribute__((address_space(3))) unsigned int*)l, 16, 0, 0);
}
#else
static __device__ __forceinline__ void STAGE16(const void* g, void* l) {
  *(float4*)l = *(const float4*)g;
}
#endif

static __device__ __forceinline__ unsigned int pk2(float a, float b) {
  __hip_bfloat162 h = __float22bfloat162_rn(make_float2(a, b));
  union { __hip_bfloat162 h; unsigned int u; } c; c.h = h;
  return c.u;
}

// merged prep: fq[b,h,:] = q[b]@Wq[h]+bq[h] (kept in LDS), then
// v[b,h,k] = Wf[h,k,:]·fq, packed bf16 B-fragments (zeros at dl=8+h)
__global__ __launch_bounds__(256) void prep(const float* __restrict__ qin,
    const float* __restrict__ Wq, const float* __restrict__ bq,
    const float* __restrict__ Wf, unsigned short* __restrict__ vB) {
  __shared__ float qs[DQ_];
  __shared__ float red[4][D_];
  __shared__ float fql[D_];
  int bh = blockIdx.x, b = bh >> 3, h = bh & 7;
  int tid = threadIdx.x, d = tid & 63, fc = tid >> 6;
  qs[tid] = qin[(size_t)b * DQ_ + tid];
  qs[tid + 256] = qin[(size_t)b * DQ_ + tid + 256];
  __syncthreads();
  {
    const float* w = Wq + (size_t)h * DQ_ * D_ + (size_t)fc * 128 * D_ + d;
    float acc = 0.f;
#pragma unroll 8
    for (int i = 0; i < 128; ++i) acc += qs[fc * 128 + i] * w[(size_t)i * D_];
    red[fc][d] = acc;
  }
  __syncthreads();
  if (fc == 0)
    fql[d] = red[0][d] + red[1][d] + red[2][d] + red[3][d] + bq[h * D_ + d];
  __syncthreads();
  // v phase: k = tid (256 rows of Wf[h])
  const float4* wr = (const float4*)(Wf + (size_t)h * DF_ * D_ + (size_t)tid * D_);
  const float4* f4 = (const float4*)fql;
  float acc = 0.f;
#pragma unroll
  for (int i = 0; i < 16; ++i) {
    float4 wv = wr[i], fv = f4[i];
    acc += wv.x * fv.x + wv.y * fv.y + wv.z * fv.z + wv.w * fv.w;
  }
  int ks = tid >> 5, kg = (tid >> 3) & 3, j = tid & 7;
  size_t base = (size_t)b * 4096 + ks * 512;
  vB[base + (kg * 16 + h) * 8 + j] = (unsigned short)(pk2(acc, 0.f) & 0xFFFF);
  vB[base + (kg * 16 + 8 + h) * 8 + j] = 0;
}

// Main: 512 blocks x 4 waves. fact DMA-staged (fp32, padded+row-permuted rows)
// double-buffered; waves split 256 features 4x64. ISSUE placed after barrier-2
// so the whole softmax+S phase covers the DMA; row-permute π kills the S-phase
// 4-way bank conflict (source-side inverse perm, read-side perm).
__global__ __launch_bounds__(256, 2) void mha_main(
    const float* __restrict__ fact, const unsigned short* __restrict__ vB,
    float* __restrict__ part_s, float* __restrict__ part_ml) {
  __shared__ char buf[2 * BUFB];        // 66560 B
  __shared__ float4 exch[2][4][64];     // 8192 B

  const int tid = threadIdx.x;
  const int l = tid & 63, w = tid >> 6;
  const int dl = l & 15, kg = l >> 4;
  const int bid = blockIdx.x;
  const int b = bid >> 3, qq = bid & 7;

  // this wave's 64-feature slice of the v B-fragments
  short8 vfrag[2];
#pragma unroll
  for (int ks = 0; ks < 2; ++ks)
    vfrag[ks] = *(const short8*)(vB + (size_t)b * 4096 + (2 * w + ks) * 512 + l * 8);

  const float* factb = fact + ((size_t)b * T_ + (size_t)qq * 512) * DF_;

  // staging map: LDS granule id -> (LDS row rho, slot); global row = pi^-1(rho)
  int srow[9], sslot[9];
#pragma unroll
  for (int i = 0; i < 9; ++i) {
    int id = i * 256 + tid;
    int rho = id / 65;
    int kgr = (rho >> 3) & 3;
    srow[i] = (rho & ~7) | (((rho & 7) + 8 - 2 * kgr) & 7);
    sslot[i] = id % 65;
  }

  // A-side LDS rows for lane's tiles (pi applied)
  const int t0 = dl, t1 = 16 + dl;
  const int lr0 = (t0 & ~7) | (((t0 & 7) + 2 * ((t0 >> 3) & 3)) & 7);
  const int lr1 = (t1 & ~7) | (((t1 & 7) + 2 * ((t1 >> 3) & 3)) & 7);
  const int aoff0 = lr0 * ROWB + (w * 64 + kg * 8) * 4;
  const int aoff1 = lr1 * ROWB + (w * 64 + kg * 8) * 4;
  // S-side LDS row byte offsets for k-rows kg*8+j (pi applied)
  int roff[8];
#pragma unroll
  for (int j = 0; j < 8; ++j)
    roff[j] = (kg * 8 + ((j + 2 * kg) & 7)) * ROWB;

#define ISSUE(C) {                                                            \
    const char* gsrc = (const char*)(factb + (size_t)(C) * CHUNK * DF_);      \
    char* ldst = buf + ((C) & 1) * BUFB;                                      \
    _Pragma("unroll") for (int i = 0; i < 9; ++i) {                           \
      int id = i * 256 + tid;                                                 \
      if (i < 8 || id < SLOTS) {                                              \
        const void* sp = (sslot[i] < 64)                                      \
            ? (const void*)(gsrc + (size_t)srow[i] * 1024 + sslot[i] * 16)    \
            : (const void*)gsrc;                                              \
        STAGE16(sp, (void*)(ldst + id * 16));                                 \
      } } }

  float m_run = -INFINITY, l_part = 0.f;
  f32x4 acc_s[4];
#pragma unroll
  for (int n = 0; n < 4; ++n) { f32x4 z = {0.f, 0.f, 0.f, 0.f}; acc_s[n] = z; }

  ISSUE(0);

  for (int c = 0; c < NCH; ++c) {
    __syncthreads(); // chunk c DMA drained; exch from c-1 fully consumed
    const char* bc = buf + (c & 1) * BUFB;

    // ---- part 1: per-tile A-fragments + K=64 logit partials ----
    f32x4 dp[2];
#pragma unroll
    for (int t2 = 0; t2 < 2; ++t2) {
      const char* arow = bc + (t2 ? aoff1 : aoff0);
      float4 a0 = *(const float4*)arow;
      float4 a1 = *(const float4*)(arow + 16);
      float4 a2 = *(const float4*)(arow + 128);
      float4 a3 = *(const float4*)(arow + 144);
      U8 af0, af1;
      af0.u.x = pk2(a0.x, a0.y); af0.u.y = pk2(a0.z, a0.w);
      af0.u.z = pk2(a1.x, a1.y); af0.u.w = pk2(a1.z, a1.w);
      af1.u.x = pk2(a2.x, a2.y); af1.u.y = pk2(a2.z, a2.w);
      af1.u.z = pk2(a3.x, a3.y); af1.u.w = pk2(a3.z, a3.w);
      f32x4 d_ = {0.f, 0.f, 0.f, 0.f};
      d_ = __builtin_amdgcn_mfma_f32_16x16x32_bf16(af0.s, vfrag[0], d_, 0, 0, 0);
      d_ = __builtin_amdgcn_mfma_f32_16x16x32_bf16(af1.s, vfrag[1], d_, 0, 0, 0);
      dp[t2] = d_;
      exch[t2][w][l] = make_float4(d_[0], d_[1], d_[2], d_[3]);
    }
    __syncthreads(); // exch visible (no vmem outstanding here)

    if (c + 1 < NCH) ISSUE(c + 1); // covered by softmax + S-phase below

    f32x4 l0 = dp[0], l1 = dp[1];
#pragma unroll
    for (int ww = 1; ww < 4; ++ww) {
      int o = (w + ww) & 3;
      float4 p0 = exch[0][o][l], p1 = exch[1][o][l];
      l0[0] += p0.x; l0[1] += p0.y; l0[2] += p0.z; l0[3] += p0.w;
      l1[0] += p1.x; l1[1] += p1.y; l1[2] += p1.z; l1[3] += p1.w;
    }

    // ---- online softmax: lane(dl=h) rows t = kg*4+r (+16 for l1) ----
    float tmax = fmaxf(fmaxf(fmaxf(l0[0], l0[1]), fmaxf(l0[2], l0[3])),
                       fmaxf(fmaxf(l1[0], l1[1]), fmaxf(l1[2], l1[3])));
    tmax = fmaxf(tmax, __shfl_xor(tmax, 16));
    tmax = fmaxf(tmax, __shfl_xor(tmax, 32));
    int need = (tmax > m_run + 8.f) && (dl < 8);
    if (__any(need)) {
      float mnew = fmaxf(m_run, tmax);
      float f = __expf(m_run - mnew);
      m_run = mnew;
      l_part *= f;
      float f0 = __shfl(f, kg * 4 + 0), f1 = __shfl(f, kg * 4 + 1);
      float f2 = __shfl(f, kg * 4 + 2), f3 = __shfl(f, kg * 4 + 3);
      if (kg < 2) {
#pragma unroll
        for (int n = 0; n < 4; ++n) {
          acc_s[n][0] *= f0; acc_s[n][1] *= f1; acc_s[n][2] *= f2; acc_s[n][3] *= f3;
        }
      }
    }
    float e0 = __expf(l0[0] - m_run), e1 = __expf(l0[1] - m_run);
    float e2 = __expf(l0[2] - m_run), e3 = __expf(l0[3] - m_run);
    float e4 = __expf(l1[0] - m_run), e5 = __expf(l1[1] - m_run);
    float e6 = __expf(l1[2] - m_run), e7 = __expf(l1[3] - m_run);
    l_part += (e0 + e1 + e2 + e3) + (e4 + e5 + e6 + e7);

    unsigned int pk00 = pk2(e0, e1), pk01 = pk2(e2, e3);
    unsigned int pk10 = pk2(e4, e5), pk11 = pk2(e6, e7);
    if (dl == 8) { pk00 = pk01 = pk10 = pk11 = 0x3F803F80u; } // ones -> colsum

    int sa = dl + ((kg & 1) ? 32 : 0);
    int sb = sa + 16;
    unsigned int g00 = __shfl(pk00, sa), g01 = __shfl(pk01, sa);
    unsigned int g02 = __shfl(pk00, sb), g03 = __shfl(pk01, sb);
    unsigned int g10 = __shfl(pk10, sa), g11 = __shfl(pk11, sa);
    unsigned int g12 = __shfl(pk10, sb), g13 = __shfl(pk11, sb);
    U8 eA;
    eA.u.x = (kg < 2) ? g00 : g10;
    eA.u.y = (kg < 2) ? g01 : g11;
    eA.u.z = (kg < 2) ? g02 : g12;
    eA.u.w = (kg < 2) ? g03 : g13;

    // ---- S += e^T @ chunk; B-fragments via permuted column walk (2-way) ----
#pragma unroll
    for (int n = 0; n < 4; ++n) {
      const char* srd = bc + (size_t)(w * 64 + n * 16 + dl) * 4;
      float b0 = *(const float*)(srd + roff[0]);
      float b1 = *(const float*)(srd + roff[1]);
      float b2 = *(const float*)(srd + roff[2]);
      float b3 = *(const float*)(srd + roff[3]);
      float b4 = *(const float*)(srd + roff[4]);
      float b5 = *(const float*)(srd + roff[5]);
      float b6 = *(const float*)(srd + roff[6]);
      float b7 = *(const float*)(srd + roff[7]);
      U8 bb;
      bb.u.x = pk2(b0, b1); bb.u.y = pk2(b2, b3);
      bb.u.z = pk2(b4, b5); bb.u.w = pk2(b6, b7);
      acc_s[n] = __builtin_amdgcn_mfma_f32_16x16x32_bf16(eA.s, bb.s, acc_s[n], 0, 0, 0);
    }
  }

  // ---- epilogue ----
  l_part += __shfl_xor(l_part, 16);
  l_part += __shfl_xor(l_part, 32);
  if (w == 0 && l < 8) {
    part_ml[(size_t)bid * 16 + l] = m_run;
    part_ml[(size_t)bid * 16 + 8 + l] = l_part;
  }
  float* ps = part_s + (size_t)bid * PS_STRIDE;
  if (kg < 2) {
#pragma unroll
    for (int n = 0; n < 4; ++n) {
      int f = w * 64 + n * 16 + dl;
      ps[(kg * 4 + 0) * 256 + f] = acc_s[n][0];
      ps[(kg * 4 + 1) * 256 + f] = acc_s[n][1];
      ps[(kg * 4 + 2) * 256 + f] = acc_s[n][2];
      ps[(kg * 4 + 3) * 256 + f] = acc_s[n][3];
    }
  } else if (kg == 2) {
#pragma unroll
    for (int n = 0; n < 4; ++n)
      ps[8 * 256 + w * 64 + n * 16 + dl] = acc_s[n][0]; // colsum row
  }
}

// combine 8 block-partials per (b,h); project through Wf[h]; add bias terms
__global__ __launch_bounds__(256) void reduce_k(const float* __restrict__ part_s,
    const float* __restrict__ part_ml, const float* __restrict__ Wf,
    const float* __restrict__ bf, float* __restrict__ out) {
  __shared__ float s_l[DF_];
  __shared__ float red[4][D_];
  int bh = blockIdx.x, b = bh >> 3, h = bh & 7;
  int tid = threadIdx.x, d = tid & 63, fc = tid >> 6;
  float M = -INFINITY;
  float mq[8];
#pragma unroll
  for (int q = 0; q < 8; ++q) {
    mq[q] = part_ml[(size_t)(b * 8 + q) * 16 + h];
    M = fmaxf(M, mq[q]);
  }
  float L = 0.f, sa = 0.f, cs = 0.f;
#pragma unroll
  for (int q = 0; q < 8; ++q) {
    float e = __expf(mq[q] - M);
    L += e * part_ml[(size_t)(b * 8 + q) * 16 + 8 + h];
    const float* ps = part_s + (size_t)(b * 8 + q) * PS_STRIDE;
    sa += e * ps[h * 256 + tid];
    cs += ps[8 * 256 + tid];
  }
  s_l[tid] = sa / L + EPS_ * cs;
  __syncthreads();
  const float* wbase = Wf + (size_t)h * DF_ * D_ + (size_t)fc * 64 * D_ + d;
  float o = 0.f;
#pragma unroll 8
  for (int k = 0; k < 64; ++k) o += s_l[fc * 64 + k] * wbase[(size_t)k * D_];
  red[fc][d] = o;
  __syncthreads();
  if (fc == 0)
    out[(size_t)b * (H_ * D_) + h * D_ + d] =
        o + red[1][d] + red[2][d] + red[3][d] + (1.f + (float)T_ * EPS_) * bf[h * D_ + d];
}

extern "C" void kernel_launch(void* const* d_in, const int* in_sizes, int n_in,
                              void* d_out, int out_size, void* d_ws, size_t ws_size,
                              hipStream_t stream) {
  const float* query = (const float*)d_in[0];
  const float* fact  = (const float*)d_in[1];
  const float* Wq    = (const float*)d_in[2];
  const float* bq    = (const float*)d_in[3];
  const float* Wf    = (const float*)d_in[4];
  const float* bf    = (const float*)d_in[5];
  float* out = (float*)d_out;

  char* ws = (char*)d_ws;
  unsigned short* vB = (unsigned short*)ws;                // 524288 B
  float* part_ml = (float*)(ws + 524288);                  // 32768 B
  float* part_s = (float*)(ws + 557056);                   // 4718592 B

  prep<<<dim3(B_ * H_), dim3(256), 0, stream>>>(query, Wq, bq, Wf, vB);
  mha_main<<<dim3(NBLK), dim3(256), 0, stream>>>(fact, vB, part_s, part_ml);
  reduce_k<<<dim3(B_ * H_), dim3(256), 0, stream>>>(part_s, part_ml, Wf, bf, out);
}

// Round 12
// 67.460 us; speedup vs baseline: 1.4230x; 1.0140x over previous
//
#include <hip/hip_runtime.h>
#include <hip/hip_bf16.h>

#define B_ 64
#define T_ 4096
#define DQ_ 512
#define DF_ 256
#define H_ 8
#define D_ 64
#define EPS_ 1e-7f
#define NBLK 512        /* (b, qq): 8 blocks per batch, 512 rows each */
#define CHUNK 32        /* rows per staged chunk */
#define NCH 16          /* chunks per block */
#define PS_STRIDE 2304  /* per-block partial: 9 rows x 256 */
#define ROWB 1040       /* padded LDS row bytes (65 16B slots) */
#define SLOTS 2080      /* 32 rows x 65 slots (slot 64 = pad) */
#define BUFB (SLOTS * 16)

typedef __attribute__((ext_vector_type(8))) short short8;
typedef __attribute__((ext_vector_type(4))) float f32x4;

union U8 { uint4 u; short8 s; };

#if defined(__has_builtin)
#if __has_builtin(__builtin_amdgcn_global_load_lds)
#define HAVE_GLL 1
#endif
#endif

#ifdef HAVE_GLL
static __device__ __forceinline__ void STAGE16(const void* g, void* l) {
  __builtin_amdgcn_global_load_lds(
      (const __attribute__((address_space(1))) unsigned int*)g,
      (__attribute__((address_space(3))) unsigned int*)l, 16, 0, 0);
}
#else
static __device__ __forceinline__ void STAGE16(const void* g, void* l) {
  *(float4*)l = *(const float4*)g;
}
#endif

static __device__ __forceinline__ unsigned int pk2(float a, float b) {
  __hip_bfloat162 h = __float22bfloat162_rn(make_float2(a, b));
  union { __hip_bfloat162 h; unsigned int u; } c; c.h = h;
  return c.u;
}

// merged prep: fq[b,h,:] = q[b]@Wq[h]+bq[h] (kept in LDS), then
// v[b,h,k] = Wf[h,k,:]·fq, packed bf16 B-fragments (zeros at dl=8+h)
__global__ __launch_bounds__(256) void prep(const float* __restrict__ qin,
    const float* __restrict__ Wq, const float* __restrict__ bq,
    const float* __restrict__ Wf, unsigned short* __restrict__ vB) {
  __shared__ float qs[DQ_];
  __shared__ float red[4][D_];
  __shared__ float fql[D_];
  int bh = blockIdx.x, b = bh >> 3, h = bh & 7;
  int tid = threadIdx.x, d = tid & 63, fc = tid >> 6;
  qs[tid] = qin[(size_t)b * DQ_ + tid];
  qs[tid + 256] = qin[(size_t)b * DQ_ + tid + 256];
  __syncthreads();
  {
    const float* w = Wq + (size_t)h * DQ_ * D_ + (size_t)fc * 128 * D_ + d;
    float acc = 0.f;
#pragma unroll 8
    for (int i = 0; i < 128; ++i) acc += qs[fc * 128 + i] * w[(size_t)i * D_];
    red[fc][d] = acc;
  }
  __syncthreads();
  if (fc == 0)
    fql[d] = red[0][d] + red[1][d] + red[2][d] + red[3][d] + bq[h * D_ + d];
  __syncthreads();
  // v phase: k = tid (256 rows of Wf[h])
  const float4* wr = (const float4*)(Wf + (size_t)h * DF_ * D_ + (size_t)tid * D_);
  const float4* f4 = (const float4*)fql;
  float acc = 0.f;
#pragma unroll
  for (int i = 0; i < 16; ++i) {
    float4 wv = wr[i], fv = f4[i];
    acc += wv.x * fv.x + wv.y * fv.y + wv.z * fv.z + wv.w * fv.w;
  }
  int ks = tid >> 5, kg = (tid >> 3) & 3, j = tid & 7;
  size_t base = (size_t)b * 4096 + ks * 512;
  vB[base + (kg * 16 + h) * 8 + j] = (unsigned short)(pk2(acc, 0.f) & 0xFFFF);
  vB[base + (kg * 16 + 8 + h) * 8 + j] = 0;
}

// Main: r11 structure (512 blocks x 4 waves, 2 blocks/CU, double buffer,
// split-K logits + LDS exchange, pi-row-permuted LDS), with ONE change:
// S-phase reads b64 feature-pairs (even/odd interleaved col mapping) ->
// 16 ds_read_b64 instead of 32 ds_read_b32 per wave per chunk.
__global__ __launch_bounds__(256, 2) void mha_main(
    const float* __restrict__ fact, const unsigned short* __restrict__ vB,
    float* __restrict__ part_s, float* __restrict__ part_ml) {
  __shared__ char buf[2 * BUFB];        // 66560 B
  __shared__ float4 exch[2][4][64];     // 8192 B

  const int tid = threadIdx.x;
  const int l = tid & 63, w = tid >> 6;
  const int dl = l & 15, kg = l >> 4;
  const int bid = blockIdx.x;
  const int b = bid >> 3, qq = bid & 7;

  // this wave's 64-feature slice of the v B-fragments
  short8 vfrag[2];
#pragma unroll
  for (int ks = 0; ks < 2; ++ks)
    vfrag[ks] = *(const short8*)(vB + (size_t)b * 4096 + (2 * w + ks) * 512 + l * 8);

  const float* factb = fact + ((size_t)b * T_ + (size_t)qq * 512) * DF_;

  // staging map: LDS granule id -> (LDS row rho, slot); global row = pi^-1(rho)
  int srow[9], sslot[9];
#pragma unroll
  for (int i = 0; i < 9; ++i) {
    int id = i * 256 + tid;
    int rho = id / 65;
    int kgr = (rho >> 3) & 3;
    srow[i] = (rho & ~7) | (((rho & 7) + 8 - 2 * kgr) & 7);
    sslot[i] = id % 65;
  }

  // A-side LDS rows for lane's tiles (pi applied)
  const int t0 = dl, t1 = 16 + dl;
  const int lr0 = (t0 & ~7) | (((t0 & 7) + 2 * ((t0 >> 3) & 3)) & 7);
  const int lr1 = (t1 & ~7) | (((t1 & 7) + 2 * ((t1 >> 3) & 3)) & 7);
  const int aoff0 = lr0 * ROWB + (w * 64 + kg * 8) * 4;
  const int aoff1 = lr1 * ROWB + (w * 64 + kg * 8) * 4;
  // S-side LDS row byte offsets for k-rows kg*8+j (pi applied)
  int roff[8];
#pragma unroll
  for (int j = 0; j < 8; ++j)
    roff[j] = (kg * 8 + ((j + 2 * kg) & 7)) * ROWB;

#define ISSUE(C) {                                                            \
    const char* gsrc = (const char*)(factb + (size_t)(C) * CHUNK * DF_);      \
    char* ldst = buf + ((C) & 1) * BUFB;                                      \
    _Pragma("unroll") for (int i = 0; i < 9; ++i) {                           \
      int id = i * 256 + tid;                                                 \
      if (i < 8 || id < SLOTS) {                                              \
        const void* sp = (sslot[i] < 64)                                      \
            ? (const void*)(gsrc + (size_t)srow[i] * 1024 + sslot[i] * 16)    \
            : (const void*)gsrc;                                              \
        STAGE16(sp, (void*)(ldst + id * 16));                                 \
      } } }

  float m_run = -INFINITY, l_part = 0.f;
  f32x4 acc_s[4];
#pragma unroll
  for (int n = 0; n < 4; ++n) { f32x4 z = {0.f, 0.f, 0.f, 0.f}; acc_s[n] = z; }

  ISSUE(0);

  for (int c = 0; c < NCH; ++c) {
    __syncthreads(); // chunk c DMA drained; exch from c-1 fully consumed
    const char* bc = buf + (c & 1) * BUFB;

    // ---- part 1: per-tile A-fragments + K=64 logit partials ----
    f32x4 dp[2];
#pragma unroll
    for (int t2 = 0; t2 < 2; ++t2) {
      const char* arow = bc + (t2 ? aoff1 : aoff0);
      float4 a0 = *(const float4*)arow;
      float4 a1 = *(const float4*)(arow + 16);
      float4 a2 = *(const float4*)(arow + 128);
      float4 a3 = *(const float4*)(arow + 144);
      U8 af0, af1;
      af0.u.x = pk2(a0.x, a0.y); af0.u.y = pk2(a0.z, a0.w);
      af0.u.z = pk2(a1.x, a1.y); af0.u.w = pk2(a1.z, a1.w);
      af1.u.x = pk2(a2.x, a2.y); af1.u.y = pk2(a2.z, a2.w);
      af1.u.z = pk2(a3.x, a3.y); af1.u.w = pk2(a3.z, a3.w);
      f32x4 d_ = {0.f, 0.f, 0.f, 0.f};
      d_ = __builtin_amdgcn_mfma_f32_16x16x32_bf16(af0.s, vfrag[0], d_, 0, 0, 0);
      d_ = __builtin_amdgcn_mfma_f32_16x16x32_bf16(af1.s, vfrag[1], d_, 0, 0, 0);
      dp[t2] = d_;
      exch[t2][w][l] = make_float4(d_[0], d_[1], d_[2], d_[3]);
    }
    __syncthreads(); // exch visible (no vmem outstanding here)

    if (c + 1 < NCH) ISSUE(c + 1); // covered by softmax + S-phase below

    f32x4 l0 = dp[0], l1 = dp[1];
#pragma unroll
    for (int ww = 1; ww < 4; ++ww) {
      int o = (w + ww) & 3;
      float4 p0 = exch[0][o][l], p1 = exch[1][o][l];
      l0[0] += p0.x; l0[1] += p0.y; l0[2] += p0.z; l0[3] += p0.w;
      l1[0] += p1.x; l1[1] += p1.y; l1[2] += p1.z; l1[3] += p1.w;
    }

    // ---- online softmax: lane(dl=h) rows t = kg*4+r (+16 for l1) ----
    float tmax = fmaxf(fmaxf(fmaxf(l0[0], l0[1]), fmaxf(l0[2], l0[3])),
                       fmaxf(fmaxf(l1[0], l1[1]), fmaxf(l1[2], l1[3])));
    tmax = fmaxf(tmax, __shfl_xor(tmax, 16));
    tmax = fmaxf(tmax, __shfl_xor(tmax, 32));
    int need = (tmax > m_run + 8.f) && (dl < 8);
    if (__any(need)) {
      float mnew = fmaxf(m_run, tmax);
      float f = __expf(m_run - mnew);
      m_run = mnew;
      l_part *= f;
      float f0 = __shfl(f, kg * 4 + 0), f1 = __shfl(f, kg * 4 + 1);
      float f2 = __shfl(f, kg * 4 + 2), f3 = __shfl(f, kg * 4 + 3);
      if (kg < 2) {
#pragma unroll
        for (int n = 0; n < 4; ++n) {
          acc_s[n][0] *= f0; acc_s[n][1] *= f1; acc_s[n][2] *= f2; acc_s[n][3] *= f3;
        }
      }
    }
    float e0 = __expf(l0[0] - m_run), e1 = __expf(l0[1] - m_run);
    float e2 = __expf(l0[2] - m_run), e3 = __expf(l0[3] - m_run);
    float e4 = __expf(l1[0] - m_run), e5 = __expf(l1[1] - m_run);
    float e6 = __expf(l1[2] - m_run), e7 = __expf(l1[3] - m_run);
    l_part += (e0 + e1 + e2 + e3) + (e4 + e5 + e6 + e7);

    unsigned int pk00 = pk2(e0, e1), pk01 = pk2(e2, e3);
    unsigned int pk10 = pk2(e4, e5), pk11 = pk2(e6, e7);
    if (dl == 8) { pk00 = pk01 = pk10 = pk11 = 0x3F803F80u; } // ones -> colsum

    int sa = dl + ((kg & 1) ? 32 : 0);
    int sb = sa + 16;
    unsigned int g00 = __shfl(pk00, sa), g01 = __shfl(pk01, sa);
    unsigned int g02 = __shfl(pk00, sb), g03 = __shfl(pk01, sb);
    unsigned int g10 = __shfl(pk10, sa), g11 = __shfl(pk11, sa);
    unsigned int g12 = __shfl(pk10, sb), g13 = __shfl(pk11, sb);
    U8 eA;
    eA.u.x = (kg < 2) ? g00 : g10;
    eA.u.y = (kg < 2) ? g01 : g11;
    eA.u.z = (kg < 2) ? g02 : g12;
    eA.u.w = (kg < 2) ? g03 : g13;

    // ---- S += e^T @ chunk; b64 feature-pair reads serve TWO fragments ----
    // acc_s[2p]   <-> feature w*64 + p*32 + 2*dl     (even)
    // acc_s[2p+1] <-> feature w*64 + p*32 + 2*dl + 1 (odd)
#pragma unroll
    for (int p = 0; p < 2; ++p) {
      const char* srd = bc + (size_t)(w * 64 + p * 32 + 2 * dl) * 4;
      float2 q0 = *(const float2*)(srd + roff[0]);
      float2 q1 = *(const float2*)(srd + roff[1]);
      float2 q2 = *(const float2*)(srd + roff[2]);
      float2 q3 = *(const float2*)(srd + roff[3]);
      float2 q4 = *(const float2*)(srd + roff[4]);
      float2 q5 = *(const float2*)(srd + roff[5]);
      float2 q6 = *(const float2*)(srd + roff[6]);
      float2 q7 = *(const float2*)(srd + roff[7]);
      U8 bbE, bbO;
      bbE.u.x = pk2(q0.x, q1.x); bbE.u.y = pk2(q2.x, q3.x);
      bbE.u.z = pk2(q4.x, q5.x); bbE.u.w = pk2(q6.x, q7.x);
      bbO.u.x = pk2(q0.y, q1.y); bbO.u.y = pk2(q2.y, q3.y);
      bbO.u.z = pk2(q4.y, q5.y); bbO.u.w = pk2(q6.y, q7.y);
      acc_s[2 * p] = __builtin_amdgcn_mfma_f32_16x16x32_bf16(eA.s, bbE.s, acc_s[2 * p], 0, 0, 0);
      acc_s[2 * p + 1] = __builtin_amdgcn_mfma_f32_16x16x32_bf16(eA.s, bbO.s, acc_s[2 * p + 1], 0, 0, 0);
    }
  }

  // ---- epilogue (interleaved feature mapping) ----
  l_part += __shfl_xor(l_part, 16);
  l_part += __shfl_xor(l_part, 32);
  if (w == 0 && l < 8) {
    part_ml[(size_t)bid * 16 + l] = m_run;
    part_ml[(size_t)bid * 16 + 8 + l] = l_part;
  }
  float* ps = part_s + (size_t)bid * PS_STRIDE;
  if (kg < 2) {
#pragma unroll
    for (int n = 0; n < 4; ++n) {
      int f = w * 64 + (n >> 1) * 32 + dl * 2 + (n & 1);
      ps[(kg * 4 + 0) * 256 + f] = acc_s[n][0];
      ps[(kg * 4 + 1) * 256 + f] = acc_s[n][1];
      ps[(kg * 4 + 2) * 256 + f] = acc_s[n][2];
      ps[(kg * 4 + 3) * 256 + f] = acc_s[n][3];
    }
  } else if (kg == 2) {
#pragma unroll
    for (int n = 0; n < 4; ++n) {
      int f = w * 64 + (n >> 1) * 32 + dl * 2 + (n & 1);
      ps[8 * 256 + f] = acc_s[n][0]; // colsum row
    }
  }
}

// combine 8 block-partials per (b,h); project through Wf[h]; add bias terms
__global__ __launch_bounds__(256) void reduce_k(const float* __restrict__ part_s,
    const float* __restrict__ part_ml, const float* __restrict__ Wf,
    const float* __restrict__ bf, float* __restrict__ out) {
  __shared__ float s_l[DF_];
  __shared__ float red[4][D_];
  int bh = blockIdx.x, b = bh >> 3, h = bh & 7;
  int tid = threadIdx.x, d = tid & 63, fc = tid >> 6;
  float M = -INFINITY;
  float mq[8];
#pragma unroll
  for (int q = 0; q < 8; ++q) {
    mq[q] = part_ml[(size_t)(b * 8 + q) * 16 + h];
    M = fmaxf(M, mq[q]);
  }
  float L = 0.f, sa = 0.f, cs = 0.f;
#pragma unroll
  for (int q = 0; q < 8; ++q) {
    float e = __expf(mq[q] - M);
    L += e * part_ml[(size_t)(b * 8 + q) * 16 + 8 + h];
    const float* ps = part_s + (size_t)(b * 8 + q) * PS_STRIDE;
    sa += e * ps[h * 256 + tid];
    cs += ps[8 * 256 + tid];
  }
  s_l[tid] = sa / L + EPS_ * cs;
  __syncthreads();
  const float* wbase = Wf + (size_t)h * DF_ * D_ + (size_t)fc * 64 * D_ + d;
  float o = 0.f;
#pragma unroll 8
  for (int k = 0; k < 64; ++k) o += s_l[fc * 64 + k] * wbase[(size_t)k * D_];
  red[fc][d] = o;
  __syncthreads();
  if (fc == 0)
    out[(size_t)b * (H_ * D_) + h * D_ + d] =
        o + red[1][d] + red[2][d] + red[3][d] + (1.f + (float)T_ * EPS_) * bf[h * D_ + d];
}

extern "C" void kernel_launch(void* const* d_in, const int* in_sizes, int n_in,
                              void* d_out, int out_size, void* d_ws, size_t ws_size,
                              hipStream_t stream) {
  const float* query = (const float*)d_in[0];
  const float* fact  = (const float*)d_in[1];
  const float* Wq    = (const float*)d_in[2];
  const float* bq    = (const float*)d_in[3];
  const float* Wf    = (const float*)d_in[4];
  const float* bf    = (const float*)d_in[5];
  float* out = (float*)d_out;

  char* ws = (char*)d_ws;
  unsigned short* vB = (unsigned short*)ws;                // 524288 B
  float* part_ml = (float*)(ws + 524288);                  // 32768 B
  float* part_s = (float*)(ws + 557056);                   // 4718592 B

  prep<<<dim3(B_ * H_), dim3(256), 0, stream>>>(query, Wq, bq, Wf, vB);
  mha_main<<<dim3(NBLK), dim3(256), 0, stream>>>(fact, vB, part_s, part_ml);
  reduce_k<<<dim3(B_ * H_), dim3(256), 0, stream>>>(part_s, part_ml, Wf, bf, out);
}